// Round 15
// baseline (75.577 us; speedup 1.0000x reference)
//
#include <hip/hip_runtime.h>
#include <math.h>

#define F 8
#define C 4096
#define NPAIR 36
#define EPSF 1e-8f

#define QCH 64               // q per block (halved vs R12: 2x blocks -> 2x TLP)
#define NQC (C / QCH)        // 64 q-chunks
#define NPG 32               // p-groups of 128 (4 waves x 32 p)
#define NBLK (NPG * NQC)     // 2048 blocks = 8/CU -> 8 waves/SIMD
#define XSROW 68             // 64 + 4 pad (float4-aligned rows)

#define NSB 128              // sred blocks
#define SO 116               // sout: D[36] | T[8] | G_b0[36] | G_b1[36]

// ws: part[NQC][F][C] rs-partials (8 MB) | gpart[NBLK][256] C-frags (2 MB) | sout
#define WS_PART (NQC * F * C)
#define WS_GP   (NBLK * 256)

typedef __attribute__((ext_vector_type(8))) short short8v;
typedef __attribute__((ext_vector_type(4))) float f32x4;

__device__ __forceinline__ float wave_reduce(float v) {
    #pragma unroll
    for (int off = 32; off > 0; off >>= 1) v += __shfl_down(v, off, 64);
    return v;
}

// MFMA gram + MFMA rs (indicator-B), fused. Inner loop byte-identical to
// R12 (70.9 us, absmax 0.0). ONE change: QCH 128 -> 64, grid 1024 -> 2048
// blocks = 8 blocks/CU = 8 waves/SIMD. Rationale: R11->R14 issue-slot cuts
// (22 -> 10.25/step) stopped paying at R12; measured ~94 cyc/step vs ~14
// slots = ~40% issue utilization at 4 waves/SIMD -> latency-bound. Live
// set ~50 VGPR fits the 64-reg/8-wave tier; the grid was the occupancy cap.
__global__ __launch_bounds__(256) void gramrs_kernel(const float* __restrict__ x,
                                                     float* __restrict__ part,
                                                     float* __restrict__ gpart) {
    __shared__ __align__(16) float xs[F * XSROW];   // 2.2 KB q-slice
    __shared__ float red[4 * 256];                  // 4 KB C-frag reduce
    const int tid  = threadIdx.x;
    const int lane = tid & 63;
    const int wave = tid >> 6;
    const int pg = blockIdx.x >> 6;                 // NQC == 64
    const int qc = blockIdx.x & 63;
    const int Q0 = qc * QCH;

    if (tid < 128) {    // stage q-slice: 8 factors x 16 float4
        const int sf = tid >> 4, si = tid & 15;
        *(float4*)(xs + sf * XSROW + 4 * si) =
            *(const float4*)(x + sf * C + Q0 + 4 * si);
    }

    const int f  = lane & 7;
    const int b  = (lane >> 3) & 1;
    const int hi = (lane >> 4) & 1;
    const int qq = (lane >> 5) & 1;
    const int pgbase = (pg * 4 + wave) * 32;
    const int p0 = pgbase + 16 * b + 8 * hi;

    float xp[8];
    *(float4*)&xp[0] = *(const float4*)(x + f * C + p0);
    *(float4*)&xp[4] = *(const float4*)(x + f * C + p0 + 4);

    // indicator B-frag: B[k, col] = 1.0bf16 iff pslot(k) == col
    union { unsigned u[4]; short8v v; } ind;
    {
        const int col = lane & 15, gg = lane >> 4;
        const int ea  = col - 8 * (gg & 1);
        #pragma unroll
        for (int t = 0; t < 4; ++t) {
            const unsigned lo = (ea == 2 * t)     ? 0x3F80u : 0u;
            const unsigned hb = (ea == 2 * t + 1) ? 0x3F80u : 0u;
            ind.u[t] = lo | (hb << 16);
        }
    }

    f32x4 acc    = {0.f, 0.f, 0.f, 0.f};
    f32x4 acc_rs = {0.f, 0.f, 0.f, 0.f};

    __syncthreads();

    const float* xrow = xs + f * XSROW + 32 * qq;   // contiguous 32 q for this lane
    #pragma unroll 4
    for (int s4 = 0; s4 < 8; ++s4) {
        const float4 q4 = *(const float4*)(xrow + 4 * s4);
        #pragma unroll
        for (int u = 0; u < 4; ++u) {
            const float xq = (u == 0) ? q4.x : (u == 1) ? q4.y : (u == 2) ? q4.z : q4.w;
            float d[8];
            #pragma unroll
            for (int j = 0; j < 8; ++j) d[j] = xq - xp[j];
            union { unsigned u32[4]; short8v v; } fr;
            #pragma unroll
            for (int t = 0; t < 4; ++t)
                asm("v_cvt_pk_bf16_f32 %0, abs(%1), abs(%2)"
                    : "=v"(fr.u32[t]) : "v"(d[2 * t]), "v"(d[2 * t + 1]));
            acc    = __builtin_amdgcn_mfma_f32_16x16x32_bf16(fr.v, fr.v, acc, 0, 0, 0);
            acc_rs = __builtin_amdgcn_mfma_f32_16x16x32_bf16(fr.v, ind.v, acc_rs, 0, 0, 0);
        }
    }

    // rs extraction: C layout col=lane&15 (pslot), row=(lane>>4)*4+r = f+8b
    {
        const int pslot = lane & 15;
        #pragma unroll
        for (int r = 0; r < 4; ++r) {
            const int row = (lane >> 4) * 4 + r;
            const int ff = row & 7, bb = row >> 3;
            part[(qc * F + ff) * C + (pgbase + 16 * bb + pslot)] = acc_rs[r];
        }
    }

    // gram: block-reduce the 4 waves' C fragments
    {
        const int col = lane & 15, r0 = (lane >> 4) * 4;
        #pragma unroll
        for (int r = 0; r < 4; ++r)
            red[wave * 256 + (r0 + r) * 16 + col] = acc[r];
    }
    __syncthreads();
    gpart[blockIdx.x * 256 + tid] =
        red[tid] + red[256 + tid] + red[512 + tid] + red[768 + tid];
}

// 128 blocks x 256. Block b owns 32 p: reduce 64 rs-chunks -> s_f(p), form
// D/T (wave 0); threads [64,136) reduce this block's 16 gpart rows for the
// 72 needed gram cells (36 per p-batch block).
__global__ __launch_bounds__(256) void sred_kernel(const float* __restrict__ part,
                                                   const float* __restrict__ gpart,
                                                   float* __restrict__ sout) {
    __shared__ float sp[8][F][32];
    const int tid = threadIdx.x;
    const int pi  = tid & 31;
    const int qg  = tid >> 5;
    const int b   = blockIdx.x;
    const int p   = b * 32 + pi;

    float acc[F];
    #pragma unroll
    for (int f = 0; f < F; ++f) acc[f] = 0.0f;
    #pragma unroll
    for (int q4 = 0; q4 < NQC / 8; ++q4) {
        const int qc = qg * (NQC / 8) + q4;
        #pragma unroll
        for (int f = 0; f < F; ++f) acc[f] += part[(qc * F + f) * C + p];
    }
    #pragma unroll
    for (int f = 0; f < F; ++f) sp[qg][f][pi] = acc[f];
    __syncthreads();

    if (tid < 64) {
        float vals[44];                 // D[36] | T[8]
        if (tid < 32) {
            float sv[F];
            #pragma unroll
            for (int f = 0; f < F; ++f) {
                float s = 0.f;
                #pragma unroll
                for (int g2 = 0; g2 < 8; ++g2) s += sp[g2][f][pi];
                sv[f] = s;
            }
            int k = 0;
            #pragma unroll
            for (int i = 0; i < F; ++i)
                #pragma unroll
                for (int j = i; j < F; ++j) { vals[k] = sv[i] * sv[j]; ++k; }
            #pragma unroll
            for (int f2 = 0; f2 < F; ++f2) vals[36 + f2] = sv[f2];
        } else {
            #pragma unroll
            for (int k = 0; k < 44; ++k) vals[k] = 0.f;
        }
        #pragma unroll
        for (int k = 0; k < 44; ++k) vals[k] = wave_reduce(vals[k]);
        if (tid == 0) {
            #pragma unroll
            for (int k = 0; k < 44; ++k) sout[b * SO + k] = vals[k];
        }
    } else if (tid < 64 + 72) {
        const int e  = tid - 64;
        const int eb = (e >= 36) ? e - 36 : e;
        int i = 0, j = eb;                          // unrank i<=j pair
        while (j >= F - i) { j -= F - i; ++i; }
        j += i;
        const int ci = (e >= 36) ? (8 + i) * 16 + (8 + j) : i * 16 + j;
        float s = 0.f;
        #pragma unroll
        for (int r = 0; r < 16; ++r) s += gpart[(b * 16 + r) * 256 + ci];
        sout[b * SO + 44 + e] = s;
    }
}

__global__ __launch_bounds__(256) void finish_kernel(const float* __restrict__ sout,
                                                     float* __restrict__ out) {
    // A: D[0,36) | T[36,44) | G_b0[44,80) | G_b1[80,116)
    __shared__ float fA[SO][2];
    __shared__ float A[SO];
    const int tid = threadIdx.x;
    if (tid < SO * 2) {
        const int colx = tid >> 1, h = tid & 1;
        float s = 0.f;
        #pragma unroll 16
        for (int i = 0; i < NSB / 2; ++i)
            s += sout[(h * (NSB / 2) + i) * SO + colx];
        fA[colx][h] = s;
    }
    __syncthreads();
    if (tid < SO) A[tid] = fA[tid][0] + fA[tid][1];
    __syncthreads();
    if (tid == 0) {
        const float invC  = 1.0f / (float)C;   // 2^-12, exact
        const float invC2 = invC * invC;       // 2^-24, exact
        float dcov[NPAIR], diag[F];
        int k = 0;
        for (int i = 0; i < F; ++i)
            for (int j = i; j < F; ++j) {
                const float G = A[44 + k] + A[80 + k];   // two p-batch blocks
                // S_ij = G/C^2 - 2 D/C^3 + T_i T_j / C^4
                const float S = G * invC2 - 2.0f * A[k] * invC2 * invC
                              + (A[36 + i] * invC2) * (A[36 + j] * invC2);
                const float dc = __builtin_amdgcn_sqrtf(fmaxf(S, 0.0f) + EPSF);
                dcov[k] = dc;
                if (i == j) diag[i] = dc;
                ++k;
            }
        float cor = 0.f;
        k = 0;
        for (int i = 0; i < F; ++i)
            for (int j = i; j < F; ++j) {
                if (j > i)
                    cor += dcov[k] * __builtin_amdgcn_rcpf(
                               __builtin_amdgcn_sqrtf(diag[i] * diag[j] + EPSF));
                ++k;
            }
        out[0] = cor;
    }
}

extern "C" void kernel_launch(void* const* d_in, const int* in_sizes, int n_in,
                              void* d_out, int out_size, void* d_ws, size_t ws_size,
                              hipStream_t stream) {
    const float* x = (const float*)d_in[0];
    float* part  = (float*)d_ws;
    float* gpart = part + WS_PART;
    float* sout  = gpart + WS_GP;
    float* out   = (float*)d_out;

    hipLaunchKernelGGL(gramrs_kernel, dim3(NBLK), dim3(256), 0, stream, x, part, gpart);
    hipLaunchKernelGGL(sred_kernel,   dim3(NSB),  dim3(256), 0, stream, part, gpart, sout);
    hipLaunchKernelGGL(finish_kernel, dim3(1),    dim3(256), 0, stream, sout, out);
}

// Round 16
// 70.416 us; speedup vs baseline: 1.0733x; 1.0733x over previous
//
#include <hip/hip_runtime.h>
#include <math.h>

#define F 8
#define C 4096
#define NPAIR 36
#define EPSF 1e-8f

#define QCH 128              // q per block
#define NQC (C / QCH)        // 32 q-chunks
#define NPG 32               // p-groups of 128 (4 waves x 32 p)
#define NBLK (NPG * NQC)     // 1024 blocks = 4/CU
#define XSROW 132            // 128 + 4 pad (132 = 4*33: float4-aligned rows)

#define NSB 128              // sred blocks
#define SO 116               // sout: D[36] | T[8] | G_b0[36] | G_b1[36]

// ws: part[NQC][F][C] rs-partials (4 MB) | gpart[NBLK][256] C-frags (1 MB) | sout
#define WS_PART (NQC * F * C)
#define WS_GP   (NBLK * 256)

typedef __attribute__((ext_vector_type(8))) short short8v;
typedef __attribute__((ext_vector_type(4))) float f32x4;

__device__ __forceinline__ float wave_reduce(float v) {
    #pragma unroll
    for (int off = 32; off > 0; off >>= 1) v += __shfl_down(v, off, 64);
    return v;
}

// MFMA gram + MFMA rs (indicator-B), fused. Wave = 32 p x 128 q.
// Lane decode: f=lane&7, b=bit3 (p-batch), hi=bit4 (p-octet), qq=bit5.
// q-mapping: lane's q = 64*qq + s (contiguous -> ds_read_b128 per 4 steps).
// Gram: same frag as A and B => C diag 8x8 blocks = per-batch factor grams
// (enumeration-invariant). rs: D_rs = |d| . IND where IND[k][col] =
// delta(pslot(k), col), pslot(k=(g,e)) = 8*(g&1)+e -> D_rs[f+8b][pslot] =
// sum_q |d_f(p,q)| in f32 (products vs exact 1.0). Best-measured config:
// 70.9 us total, absmax 0.0 (R12). Terminal: gram time is invariant to
// occupancy (R15), issue width (R14), memory path (R2-R10); the 41 us
// harness fill runs at 81-84% HBM peak and bounds the total from below.
__global__ __launch_bounds__(256) void gramrs_kernel(const float* __restrict__ x,
                                                     float* __restrict__ part,
                                                     float* __restrict__ gpart) {
    __shared__ __align__(16) float xs[F * XSROW];   // 4.2 KB q-slice
    __shared__ float red[4 * 256];                  // 4 KB C-frag reduce
    const int tid  = threadIdx.x;
    const int lane = tid & 63;
    const int wave = tid >> 6;
    const int pg = blockIdx.x >> 5;                 // NQC == 32
    const int qc = blockIdx.x & 31;
    const int Q0 = qc * QCH;

    {   // stage q-slice: 8 factors x 32 float4 = 256 threads, one each
        const int sf = tid >> 5, si = tid & 31;
        *(float4*)(xs + sf * XSROW + 4 * si) =
            *(const float4*)(x + sf * C + Q0 + 4 * si);
    }

    const int f  = lane & 7;
    const int b  = (lane >> 3) & 1;
    const int hi = (lane >> 4) & 1;
    const int qq = (lane >> 5) & 1;
    const int pgbase = (pg * 4 + wave) * 32;
    const int p0 = pgbase + 16 * b + 8 * hi;

    float xp[8];
    *(float4*)&xp[0] = *(const float4*)(x + f * C + p0);
    *(float4*)&xp[4] = *(const float4*)(x + f * C + p0 + 4);

    // indicator B-frag: lane (col=lane&15, g=lane>>4) element e is bf16 1.0
    // iff 8*(g&1)+e == col, else 0. At most one nonzero per lane.
    union { unsigned u[4]; short8v v; } ind;
    {
        const int col = lane & 15, gg = lane >> 4;
        const int ea  = col - 8 * (gg & 1);         // active e, or out of range
        #pragma unroll
        for (int t = 0; t < 4; ++t) {
            const unsigned lo = (ea == 2 * t)     ? 0x3F80u : 0u;
            const unsigned hb = (ea == 2 * t + 1) ? 0x3F80u : 0u;
            ind.u[t] = lo | (hb << 16);
        }
    }

    f32x4 acc    = {0.f, 0.f, 0.f, 0.f};
    f32x4 acc_rs = {0.f, 0.f, 0.f, 0.f};

    __syncthreads();

    const float* xrow = xs + f * XSROW + 64 * qq;   // contiguous 64 q for this lane
    #pragma unroll 4
    for (int s4 = 0; s4 < 16; ++s4) {
        const float4 q4 = *(const float4*)(xrow + 4 * s4);
        #pragma unroll
        for (int u = 0; u < 4; ++u) {
            const float xq = (u == 0) ? q4.x : (u == 1) ? q4.y : (u == 2) ? q4.z : q4.w;
            float d[8];
            #pragma unroll
            for (int j = 0; j < 8; ++j) d[j] = xq - xp[j];
            union { unsigned u32[4]; short8v v; } fr;
            #pragma unroll
            for (int t = 0; t < 4; ++t)
                asm("v_cvt_pk_bf16_f32 %0, abs(%1), abs(%2)"
                    : "=v"(fr.u32[t]) : "v"(d[2 * t]), "v"(d[2 * t + 1]));
            acc    = __builtin_amdgcn_mfma_f32_16x16x32_bf16(fr.v, fr.v, acc, 0, 0, 0);
            acc_rs = __builtin_amdgcn_mfma_f32_16x16x32_bf16(fr.v, ind.v, acc_rs, 0, 0, 0);
        }
    }

    // rs extraction: C layout col=lane&15 (pslot), row=(lane>>4)*4+r = f+8b
    {
        const int pslot = lane & 15;
        #pragma unroll
        for (int r = 0; r < 4; ++r) {
            const int row = (lane >> 4) * 4 + r;
            const int ff = row & 7, bb = row >> 3;
            part[(qc * F + ff) * C + (pgbase + 16 * bb + pslot)] = acc_rs[r];
        }
    }

    // gram: block-reduce the 4 waves' C fragments
    {
        const int col = lane & 15, r0 = (lane >> 4) * 4;
        #pragma unroll
        for (int r = 0; r < 4; ++r)
            red[wave * 256 + (r0 + r) * 16 + col] = acc[r];
    }
    __syncthreads();
    gpart[blockIdx.x * 256 + tid] =
        red[tid] + red[256 + tid] + red[512 + tid] + red[768 + tid];
}

// 128 blocks x 256. Block b owns 32 p: reduce 32 rs-chunks -> s_f(p), form
// D/T (wave 0); threads [64,136) reduce this block's 8 gpart rows for the
// 72 needed gram cells (36 per p-batch block).
__global__ __launch_bounds__(256) void sred_kernel(const float* __restrict__ part,
                                                   const float* __restrict__ gpart,
                                                   float* __restrict__ sout) {
    __shared__ float sp[8][F][32];
    const int tid = threadIdx.x;
    const int pi  = tid & 31;
    const int qg  = tid >> 5;
    const int b   = blockIdx.x;
    const int p   = b * 32 + pi;

    float acc[F];
    #pragma unroll
    for (int f = 0; f < F; ++f) acc[f] = 0.0f;
    #pragma unroll
    for (int q4 = 0; q4 < NQC / 8; ++q4) {
        const int qc = qg * (NQC / 8) + q4;
        #pragma unroll
        for (int f = 0; f < F; ++f) acc[f] += part[(qc * F + f) * C + p];
    }
    #pragma unroll
    for (int f = 0; f < F; ++f) sp[qg][f][pi] = acc[f];
    __syncthreads();

    if (tid < 64) {
        float vals[44];                 // D[36] | T[8]
        if (tid < 32) {
            float sv[F];
            #pragma unroll
            for (int f = 0; f < F; ++f) {
                float s = 0.f;
                #pragma unroll
                for (int g2 = 0; g2 < 8; ++g2) s += sp[g2][f][pi];
                sv[f] = s;
            }
            int k = 0;
            #pragma unroll
            for (int i = 0; i < F; ++i)
                #pragma unroll
                for (int j = i; j < F; ++j) { vals[k] = sv[i] * sv[j]; ++k; }
            #pragma unroll
            for (int f2 = 0; f2 < F; ++f2) vals[36 + f2] = sv[f2];
        } else {
            #pragma unroll
            for (int k = 0; k < 44; ++k) vals[k] = 0.f;
        }
        #pragma unroll
        for (int k = 0; k < 44; ++k) vals[k] = wave_reduce(vals[k]);
        if (tid == 0) {
            #pragma unroll
            for (int k = 0; k < 44; ++k) sout[b * SO + k] = vals[k];
        }
    } else if (tid < 64 + 72) {
        const int e  = tid - 64;
        const int eb = (e >= 36) ? e - 36 : e;
        int i = 0, j = eb;                          // unrank i<=j pair
        while (j >= F - i) { j -= F - i; ++i; }
        j += i;
        const int ci = (e >= 36) ? (8 + i) * 16 + (8 + j) : i * 16 + j;
        float s = 0.f;
        #pragma unroll
        for (int r = 0; r < 8; ++r) s += gpart[(b * 8 + r) * 256 + ci];
        sout[b * SO + 44 + e] = s;
    }
}

__global__ __launch_bounds__(256) void finish_kernel(const float* __restrict__ sout,
                                                     float* __restrict__ out) {
    // A: D[0,36) | T[36,44) | G_b0[44,80) | G_b1[80,116)
    __shared__ float fA[SO][2];
    __shared__ float A[SO];
    const int tid = threadIdx.x;
    if (tid < SO * 2) {
        const int colx = tid >> 1, h = tid & 1;
        float s = 0.f;
        #pragma unroll 16
        for (int i = 0; i < NSB / 2; ++i)
            s += sout[(h * (NSB / 2) + i) * SO + colx];
        fA[colx][h] = s;
    }
    __syncthreads();
    if (tid < SO) A[tid] = fA[tid][0] + fA[tid][1];
    __syncthreads();
    if (tid == 0) {
        const float invC  = 1.0f / (float)C;   // 2^-12, exact
        const float invC2 = invC * invC;       // 2^-24, exact
        float dcov[NPAIR], diag[F];
        int k = 0;
        for (int i = 0; i < F; ++i)
            for (int j = i; j < F; ++j) {
                const float G = A[44 + k] + A[80 + k];   // two p-batch blocks
                // S_ij = G/C^2 - 2 D/C^3 + T_i T_j / C^4
                const float S = G * invC2 - 2.0f * A[k] * invC2 * invC
                              + (A[36 + i] * invC2) * (A[36 + j] * invC2);
                const float dc = __builtin_amdgcn_sqrtf(fmaxf(S, 0.0f) + EPSF);
                dcov[k] = dc;
                if (i == j) diag[i] = dc;
                ++k;
            }
        float cor = 0.f;
        k = 0;
        for (int i = 0; i < F; ++i)
            for (int j = i; j < F; ++j) {
                if (j > i)
                    cor += dcov[k] * __builtin_amdgcn_rcpf(
                               __builtin_amdgcn_sqrtf(diag[i] * diag[j] + EPSF));
                ++k;
            }
        out[0] = cor;
    }
}

extern "C" void kernel_launch(void* const* d_in, const int* in_sizes, int n_in,
                              void* d_out, int out_size, void* d_ws, size_t ws_size,
                              hipStream_t stream) {
    const float* x = (const float*)d_in[0];
    float* part  = (float*)d_ws;
    float* gpart = part + WS_PART;
    float* sout  = gpart + WS_GP;
    float* out   = (float*)d_out;

    hipLaunchKernelGGL(gramrs_kernel, dim3(NBLK), dim3(256), 0, stream, x, part, gpart);
    hipLaunchKernelGGL(sred_kernel,   dim3(NSB),  dim3(256), 0, stream, part, gpart, sout);
    hipLaunchKernelGGL(finish_kernel, dim3(1),    dim3(256), 0, stream, sout, out);
}